// Round 2
// baseline (51.188 us; speedup 1.0000x reference)
//
#include <hip/hip_runtime.h>

// SVR inference: out[i] = sum_j exp(-|f_i - f_j|^2 / (2*sigma^2)) * alpha[j] + bias
// N = 4096 rows, D = 64 features, sigma = 5.
//
// Round 2: force i-row residency in VGPRs (named float4 vars — R1 showed the
// compiler demoted fi[64] array to re-loads: VGPR_Count=40), and raise
// occupancy (JCHUNK 128->64 => 1024 blocks = 4 blocks/CU; launch_bounds(256,4)
// caps VGPRs at 128 so 4 blocks/CU actually fit).
// fj stays wave-uniform -> s_load into SGPRs (R1: SGPR_Count=96 confirms).

#define NN 4096
#define DD 64
#define JCHUNK 64

__global__ __launch_bounds__(256) void svr_prep(const float* __restrict__ F,
                                                const float* __restrict__ bias,
                                                float* __restrict__ sq,
                                                float* __restrict__ out) {
    int i = blockIdx.x * 256 + threadIdx.x;
    const float4* Fr = reinterpret_cast<const float4*>(F + (size_t)i * DD);
    float s = 0.f;
#pragma unroll
    for (int d = 0; d < DD / 4; ++d) {
        float4 v = Fr[d];
        s = fmaf(v.x, v.x, s);
        s = fmaf(v.y, v.y, s);
        s = fmaf(v.z, v.z, s);
        s = fmaf(v.w, v.w, s);
    }
    sq[i] = s;
    out[i] = bias[0];   // re-initialize every call (atomics accumulate on top)
}

__global__ __launch_bounds__(256, 4) void svr_main(const float* __restrict__ F,
                                                   const float* __restrict__ alpha,
                                                   const float* __restrict__ sq,
                                                   float* __restrict__ out) {
    const int i = blockIdx.x * 256 + threadIdx.x;
    const int j0 = blockIdx.y * JCHUNK;

    // Own row in 16 NAMED float4s -> 64 VGPRs the compiler must keep resident.
    const float4* Fr = reinterpret_cast<const float4*>(F + (size_t)i * DD);
    float4 f0 = Fr[0],  f1 = Fr[1],  f2 = Fr[2],  f3 = Fr[3];
    float4 f4 = Fr[4],  f5 = Fr[5],  f6 = Fr[6],  f7 = Fr[7];
    float4 f8 = Fr[8],  f9 = Fr[9],  f10 = Fr[10], f11 = Fr[11];
    float4 f12 = Fr[12], f13 = Fr[13], f14 = Fr[14], f15 = Fr[15];

    const float sqi = sq[i];
    constexpr float kInv = 1.0f / (2.0f * 5.0f * 5.0f);   // 1/(2*sigma^2)
    float acc = 0.f;

#pragma unroll 2
    for (int j = j0; j < j0 + JCHUNK; ++j) {
        const float4* __restrict__ fj = reinterpret_cast<const float4*>(F + (size_t)j * DD);
        float p0 = 0.f, p1 = 0.f, p2 = 0.f, p3 = 0.f;   // 4 chains: ILP
        float4 b;
#define DOT4(k, fk)                                     \
        b = fj[k];                                      \
        p0 = fmaf(fk.x, b.x, p0);                       \
        p1 = fmaf(fk.y, b.y, p1);                       \
        p2 = fmaf(fk.z, b.z, p2);                       \
        p3 = fmaf(fk.w, b.w, p3);
        DOT4(0, f0)   DOT4(1, f1)   DOT4(2, f2)   DOT4(3, f3)
        DOT4(4, f4)   DOT4(5, f5)   DOT4(6, f6)   DOT4(7, f7)
        DOT4(8, f8)   DOT4(9, f9)   DOT4(10, f10) DOT4(11, f11)
        DOT4(12, f12) DOT4(13, f13) DOT4(14, f14) DOT4(15, f15)
#undef DOT4
        const float dot = (p0 + p1) + (p2 + p3);
        float d2 = fmaxf(fmaf(-2.f, dot, sqi + sq[j]), 0.f);
        acc = fmaf(__expf(-d2 * kInv), alpha[j], acc);
    }

    atomicAdd(&out[i], acc);
}

extern "C" void kernel_launch(void* const* d_in, const int* in_sizes, int n_in,
                              void* d_out, int out_size, void* d_ws, size_t ws_size,
                              hipStream_t stream) {
    const float* F     = (const float*)d_in[0];   // [4096, 64] fp32
    const float* alpha = (const float*)d_in[1];   // [4096, 1] fp32
    const float* bias  = (const float*)d_in[2];   // [1, 1]  fp32
    float* out = (float*)d_out;                   // [4096]  fp32
    float* sq  = (float*)d_ws;                    // 16 KB scratch: |f_i|^2

    // Pass 1: row squared-norms + out = bias   (must precede atomics in pass 2)
    svr_prep<<<dim3(NN / 256), dim3(256), 0, stream>>>(F, bias, sq, out);

    // Pass 2: partial kernel-matvec over j-chunks, accumulated atomically.
    svr_main<<<dim3(NN / 256, NN / JCHUNK), dim3(256), 0, stream>>>(F, alpha, sq, out);
}

// Round 4
// 30.711 us; speedup vs baseline: 1.6667x; 1.6667x over previous
//
#include <hip/hip_runtime.h>

// SVR inference: out[i] = sum_j exp(-|f_i-f_j|^2/50) * alpha[j] + bias
// N=4096, D=64. Round 4: bf16 MFMA fused kernel (flash-style), R3 retry —
// compile fix only: no hip_bf16.h; fp32->bf16 via explicit RNE bit math.
//
//  - prep: F fp32 -> bf16 (d_ws), sq2[i] = |f_i|^2/50, out[i] = bias
//  - main: per wave: 16 i-rows (B frags resident, 8 VGPRs), loop 16 j-tiles:
//      2x mfma_f32_16x16x32_bf16 -> dot(f_j, f_i) fragment
//      epilogue: exp(0.04*dot - sq2_i - sq2_j) * alpha_j, per-lane acc
//    end: sum 4 regs + shfl_xor(16,32) reduce -> atomicAdd out[i].
//  - A/B frags share the lane->k mapping => any k-permutation cancels.
//    C/D: col = lane&15 (i), row = (lane>>4)*4 + reg (j)   [verified m89]

#define NN 4096
#define DD 64
#define JC 16          // j-chunks -> grid.y; chunk = 256 j = 16 tiles

typedef __attribute__((ext_vector_type(8))) short bf16x8;
typedef __attribute__((ext_vector_type(4))) float f32x4;

__device__ __forceinline__ unsigned short f2bf_rne(float f) {
    unsigned int x = __float_as_uint(f);
    x += 0x7fffu + ((x >> 16) & 1u);      // round-to-nearest-even
    return (unsigned short)(x >> 16);
}

// ---------------- MFMA path ----------------

__global__ __launch_bounds__(256) void svr_prep_bf16(const float* __restrict__ F,
                                                     const float* __restrict__ bias,
                                                     unsigned short* __restrict__ Fb,
                                                     float* __restrict__ sq2,
                                                     float* __restrict__ out) {
    const int gid = blockIdx.x * 256 + threadIdx.x;          // 65536 float4 slots
    float4 v = reinterpret_cast<const float4*>(F)[gid];
    ushort4 u;
    u.x = f2bf_rne(v.x);
    u.y = f2bf_rne(v.y);
    u.z = f2bf_rne(v.z);
    u.w = f2bf_rne(v.w);
    reinterpret_cast<ushort4*>(Fb)[gid] = u;

    if (blockIdx.x < 16) {                                    // rows 0..4095
        const int i = gid;                                    // < 4096 here
        const float4* Fr = reinterpret_cast<const float4*>(F + (size_t)i * DD);
        float s = 0.f;
#pragma unroll
        for (int d = 0; d < DD / 4; ++d) {
            float4 w = Fr[d];
            s = fmaf(w.x, w.x, s);
            s = fmaf(w.y, w.y, s);
            s = fmaf(w.z, w.z, s);
            s = fmaf(w.w, w.w, s);
        }
        sq2[i] = s * 0.02f;       // |f_i|^2 / 50
        out[i] = bias[0];         // re-init every call (atomics accumulate)
    }
}

__global__ __launch_bounds__(256) void svr_mfma(const unsigned short* __restrict__ Fb,
                                                const float* __restrict__ alpha,
                                                const float* __restrict__ sq2,
                                                float* __restrict__ out) {
    const int lane = threadIdx.x & 63;
    const int wave = threadIdx.x >> 6;
    const int iBase = blockIdx.x * 64 + wave * 16;
    const int jBase = blockIdx.y * (NN / JC);
    const int kg = lane >> 4;            // 0..3  (k-group)
    const int c  = lane & 15;            // column / row-within-tile

    const bf16x8* F8 = reinterpret_cast<const bf16x8*>(Fb);  // row*8 + half*4 + kg

    // B fragments: the wave's 16 i-rows, resident for the whole j-loop.
    const bf16x8 b0 = F8[(size_t)(iBase + c) * 8 + kg];       // k 0..31
    const bf16x8 b1 = F8[(size_t)(iBase + c) * 8 + 4 + kg];   // k 32..63
    const float si2 = sq2[iBase + c];

    const float4* sqv = reinterpret_cast<const float4*>(sq2);
    const float4* alv = reinterpret_cast<const float4*>(alpha);

    f32x4 acc = {0.f, 0.f, 0.f, 0.f};

#pragma unroll 4
    for (int jt = 0; jt < (NN / JC) / 16; ++jt) {
        const int jr = jBase + jt * 16;
        const bf16x8 a0 = F8[(size_t)(jr + c) * 8 + kg];
        const bf16x8 a1 = F8[(size_t)(jr + c) * 8 + 4 + kg];

        f32x4 d = {0.f, 0.f, 0.f, 0.f};
        d = __builtin_amdgcn_mfma_f32_16x16x32_bf16(a0, b0, d, 0, 0, 0);
        d = __builtin_amdgcn_mfma_f32_16x16x32_bf16(a1, b1, d, 0, 0, 0);
        // d[r] = dot(f_{jr+kg*4+r}, f_{iBase+c})

        const float4 sj = sqv[jr / 4 + kg];    // sq2 of the 4 j-rows
        const float4 aj = alv[jr / 4 + kg];    // alpha of the 4 j-rows

        acc.x = fmaf(__expf(fmaf(d[0], 0.04f, -(si2 + sj.x))), aj.x, acc.x);
        acc.y = fmaf(__expf(fmaf(d[1], 0.04f, -(si2 + sj.y))), aj.y, acc.y);
        acc.z = fmaf(__expf(fmaf(d[2], 0.04f, -(si2 + sj.z))), aj.z, acc.z);
        acc.w = fmaf(__expf(fmaf(d[3], 0.04f, -(si2 + sj.w))), aj.w, acc.w);
    }

    float s = (acc.x + acc.y) + (acc.z + acc.w);
    s += __shfl_xor(s, 16);
    s += __shfl_xor(s, 32);
    if (lane < 16) atomicAdd(&out[iBase + lane], s);
}

// ---------------- fp32 fallback (proven R2 path) ----------------

__global__ __launch_bounds__(256) void svr_prep_f32(const float* __restrict__ F,
                                                    const float* __restrict__ bias,
                                                    float* __restrict__ sq,
                                                    float* __restrict__ out) {
    int i = blockIdx.x * 256 + threadIdx.x;
    const float4* Fr = reinterpret_cast<const float4*>(F + (size_t)i * DD);
    float s = 0.f;
#pragma unroll
    for (int d = 0; d < DD / 4; ++d) {
        float4 v = Fr[d];
        s = fmaf(v.x, v.x, s);
        s = fmaf(v.y, v.y, s);
        s = fmaf(v.z, v.z, s);
        s = fmaf(v.w, v.w, s);
    }
    sq[i] = s;
    out[i] = bias[0];
}

__global__ __launch_bounds__(256, 4) void svr_main_f32(const float* __restrict__ F,
                                                       const float* __restrict__ alpha,
                                                       const float* __restrict__ sq,
                                                       float* __restrict__ out) {
    const int i = blockIdx.x * 256 + threadIdx.x;
    const int j0 = blockIdx.y * 64;
    const float4* Fr = reinterpret_cast<const float4*>(F + (size_t)i * DD);
    float4 f0 = Fr[0], f1 = Fr[1], f2 = Fr[2], f3 = Fr[3];
    float4 f4 = Fr[4], f5 = Fr[5], f6 = Fr[6], f7 = Fr[7];
    float4 f8 = Fr[8], f9 = Fr[9], f10 = Fr[10], f11 = Fr[11];
    float4 f12 = Fr[12], f13 = Fr[13], f14 = Fr[14], f15 = Fr[15];
    const float sqi = sq[i];
    float acc = 0.f;
#pragma unroll 2
    for (int j = j0; j < j0 + 64; ++j) {
        const float4* __restrict__ fj = reinterpret_cast<const float4*>(F + (size_t)j * DD);
        float p0 = 0.f, p1 = 0.f, p2 = 0.f, p3 = 0.f;
        float4 b;
#define DOT4(k, fk) b = fj[k]; p0 = fmaf(fk.x, b.x, p0); p1 = fmaf(fk.y, b.y, p1); \
                    p2 = fmaf(fk.z, b.z, p2); p3 = fmaf(fk.w, b.w, p3);
        DOT4(0, f0)  DOT4(1, f1)  DOT4(2, f2)  DOT4(3, f3)
        DOT4(4, f4)  DOT4(5, f5)  DOT4(6, f6)  DOT4(7, f7)
        DOT4(8, f8)  DOT4(9, f9)  DOT4(10, f10) DOT4(11, f11)
        DOT4(12, f12) DOT4(13, f13) DOT4(14, f14) DOT4(15, f15)
#undef DOT4
        const float dot = (p0 + p1) + (p2 + p3);
        float d2 = fmaxf(fmaf(-2.f, dot, sqi + sq[j]), 0.f);
        acc = fmaf(__expf(-d2 * 0.02f), alpha[j], acc);
    }
    atomicAdd(&out[i], acc);
}

// ---------------- launch ----------------

extern "C" void kernel_launch(void* const* d_in, const int* in_sizes, int n_in,
                              void* d_out, int out_size, void* d_ws, size_t ws_size,
                              hipStream_t stream) {
    const float* F     = (const float*)d_in[0];
    const float* alpha = (const float*)d_in[1];
    const float* bias  = (const float*)d_in[2];
    float* out = (float*)d_out;

    const size_t fb_bytes = (size_t)NN * DD * 2;              // 512 KB bf16 F
    if (ws_size >= fb_bytes + NN * sizeof(float)) {
        unsigned short* Fb = (unsigned short*)d_ws;
        float* sq2 = (float*)((char*)d_ws + fb_bytes);
        svr_prep_bf16<<<dim3(NN * DD / 4 / 256), dim3(256), 0, stream>>>(F, bias, Fb, sq2, out);
        svr_mfma<<<dim3(NN / 64, JC), dim3(256), 0, stream>>>(Fb, alpha, sq2, out);
    } else {
        float* sq = (float*)d_ws;
        svr_prep_f32<<<dim3(NN / 256), dim3(256), 0, stream>>>(F, bias, sq, out);
        svr_main_f32<<<dim3(NN / 256, NN / 64), dim3(256), 0, stream>>>(F, alpha, sq, out);
    }
}

// Round 5
// 19.802 us; speedup vs baseline: 2.5849x; 1.5509x over previous
//
#include <hip/hip_runtime.h>

// SVR inference: out[i] = sum_j exp(-|f_i-f_j|^2/50) * alpha[j] + bias
// N=4096, D=64.  Round 5: MFMA path, latency fixes.
//  - prep retiles F (fp32) into bf16 FRAGMENT-ORDER chunks: chunk g holds
//    row=16*(g>>7)+(g&15... see map below) so every main-loop fragment load
//    is one fully-coalesced 1KB global_load_dwordx4 (R4 pattern split each
//    load into 16 cache lines).
//  - independent d0/d1 MFMA accumulators (R4 chained them).
//  - JC=32 -> 2048 blocks = 8 blocks/CU; __launch_bounds__(256,8).
// Frag map (16x16x32 bf16): lane l of tile t, k-half h holds
//   row = 16*t + (l&15), k = 32*h + (l>>4)*8 .. +7   -> chunk id (t*2+h)*64+l.
// A- and B-frags share the lane->k map, so any k-permutation cancels in A.B.
// C/D: col=lane&15 (i), row=(lane>>4)*4+reg (j)  [verified m89; R4 passed].

#define NN 4096
#define DD 64
#define JC 32                  // j-chunks: per block 128 j = 8 tiles
#define NT (NN / 16)           // 256 row-tiles

typedef __attribute__((ext_vector_type(8))) short bf16x8;
typedef __attribute__((ext_vector_type(8))) unsigned short u16x8;
typedef __attribute__((ext_vector_type(4))) float f32x4;

static __device__ __forceinline__ unsigned short f2bf(float f) {
    unsigned int x = __float_as_uint(f);
    x += 0x7fffu + ((x >> 16) & 1u);          // RNE
    return (unsigned short)(x >> 16);
}

// ---------------- prep: retile + convert + row norms + out=bias ----------------
// 32768 threads: one 16B output chunk each.
__global__ __launch_bounds__(256) void svr_prep(const float* __restrict__ F,
                                                const float* __restrict__ bias,
                                                u16x8* __restrict__ Ft,
                                                float* __restrict__ sq2,
                                                float* __restrict__ out) {
    const int g = blockIdx.x * 256 + threadIdx.x;   // 0..32767
    const int l = g & 63;
    const int h = (g >> 6) & 1;
    const int t = g >> 7;
    const int row = t * 16 + (l & 15);
    const int k0  = h * 32 + (l >> 4) * 8;

    const float4* src = reinterpret_cast<const float4*>(F + (size_t)row * DD + k0);
    float4 v0 = src[0];
    float4 v1 = src[1];
    u16x8 u;
    u[0] = f2bf(v0.x); u[1] = f2bf(v0.y); u[2] = f2bf(v0.z); u[3] = f2bf(v0.w);
    u[4] = f2bf(v1.x); u[5] = f2bf(v1.y); u[6] = f2bf(v1.z); u[7] = f2bf(v1.w);
    Ft[g] = u;

    if (g < NN) {                                    // per-row |f|^2/50, out=bias
        const float4* Fr = reinterpret_cast<const float4*>(F + (size_t)g * DD);
        float s = 0.f;
#pragma unroll
        for (int d = 0; d < DD / 4; ++d) {
            float4 w = Fr[d];
            s = fmaf(w.x, w.x, s);
            s = fmaf(w.y, w.y, s);
            s = fmaf(w.z, w.z, s);
            s = fmaf(w.w, w.w, s);
        }
        sq2[g] = s * 0.02f;
        out[g] = bias[0];        // re-init every call (atomics accumulate on top)
    }
}

// ---------------- main: fused gram-tile + exp + alpha matvec ----------------
__global__ __launch_bounds__(256, 8) void svr_mfma(const bf16x8* __restrict__ Ft,
                                                   const float* __restrict__ alpha,
                                                   const float* __restrict__ sq2,
                                                   float* __restrict__ out) {
    const int lane = threadIdx.x & 63;
    const int wave = threadIdx.x >> 6;
    const int it   = blockIdx.x * 4 + wave;          // i-tile 0..255
    const int iBase = it * 16;
    const int jt0  = blockIdx.y * (NT / JC);         // 8 j-tiles per block
    const int kg   = lane >> 4;
    const int c    = lane & 15;

    // B fragments: this wave's 16 i-rows, resident all loop (1KB coalesced loads).
    const bf16x8 b0 = Ft[it * 128 + lane];
    const bf16x8 b1 = Ft[it * 128 + 64 + lane];
    const float si2 = sq2[iBase + c];

    const float4* sqv = reinterpret_cast<const float4*>(sq2);
    const float4* alv = reinterpret_cast<const float4*>(alpha);

    f32x4 acc = {0.f, 0.f, 0.f, 0.f};

#pragma unroll 2
    for (int jt = jt0; jt < jt0 + NT / JC; ++jt) {
        const bf16x8 a0 = Ft[jt * 128 + lane];       // coalesced 1KB
        const bf16x8 a1 = Ft[jt * 128 + 64 + lane];

        f32x4 d0 = {0.f, 0.f, 0.f, 0.f};
        f32x4 d1 = {0.f, 0.f, 0.f, 0.f};
        d0 = __builtin_amdgcn_mfma_f32_16x16x32_bf16(a0, b0, d0, 0, 0, 0);   // k 0..31
        d1 = __builtin_amdgcn_mfma_f32_16x16x32_bf16(a1, b1, d1, 0, 0, 0);   // k 32..63
        // d0[r]+d1[r] = dot(f_{16*jt+kg*4+r}, f_{iBase+c})

        const float4 sj = sqv[jt * 4 + kg];          // sq2 of the 4 j-rows
        const float4 aj = alv[jt * 4 + kg];          // alpha of the 4 j-rows

        acc.x = fmaf(__expf(fmaf(d0[0] + d1[0], 0.04f, -(si2 + sj.x))), aj.x, acc.x);
        acc.y = fmaf(__expf(fmaf(d0[1] + d1[1], 0.04f, -(si2 + sj.y))), aj.y, acc.y);
        acc.z = fmaf(__expf(fmaf(d0[2] + d1[2], 0.04f, -(si2 + sj.z))), aj.z, acc.z);
        acc.w = fmaf(__expf(fmaf(d0[3] + d1[3], 0.04f, -(si2 + sj.w))), aj.w, acc.w);
    }

    float s = (acc.x + acc.y) + (acc.z + acc.w);
    s += __shfl_xor(s, 16);
    s += __shfl_xor(s, 32);
    if (lane < 16) atomicAdd(&out[iBase + lane], s);
}

// ---------------- launch ----------------
extern "C" void kernel_launch(void* const* d_in, const int* in_sizes, int n_in,
                              void* d_out, int out_size, void* d_ws, size_t ws_size,
                              hipStream_t stream) {
    const float* F     = (const float*)d_in[0];
    const float* alpha = (const float*)d_in[1];
    const float* bias  = (const float*)d_in[2];
    float* out = (float*)d_out;

    u16x8* Ft  = (u16x8*)d_ws;                                  // 512 KB tiled bf16
    float* sq2 = (float*)((char*)d_ws + (size_t)NN * DD * 2);   // 16 KB |f|^2/50

    svr_prep<<<dim3(NN * DD / 8 / 256), dim3(256), 0, stream>>>(F, bias, Ft, sq2, out);
    svr_mfma<<<dim3(NT / 4, JC), dim3(256), 0, stream>>>((const bf16x8*)Ft, alpha, sq2, out);
}